// Round 1
// baseline (3627.375 us; speedup 1.0000x reference)
//
#include <hip/hip_runtime.h>
#include <hip/hip_bf16.h>

#define N_USERS 100000
#define N_ITEMS 50000
#define N_NODES 150000
#define N_EDGES 4800000
#define DIM 64
#define N_LAYERS 3
#define OUT_STRIDE 256   // DIM * (N_LAYERS+1)

// ---------------------------------------------------------------------------
// concat: ego0 = [user_emb; item_emb]; also write raw ego0 into out cols 0:64
// ---------------------------------------------------------------------------
__global__ void concat_kernel(const float* __restrict__ user_emb,
                              const float* __restrict__ item_emb,
                              float* __restrict__ ego,
                              float* __restrict__ out) {
    const int total = N_NODES * DIM;
    for (int i = blockIdx.x * blockDim.x + threadIdx.x; i < total;
         i += gridDim.x * blockDim.x) {
        int node = i >> 6;
        int d    = i & 63;
        float v = (node < N_USERS) ? user_emb[i] : item_emb[i - N_USERS * DIM];
        ego[i] = v;
        out[node * OUT_STRIDE + d] = v;
    }
}

// ---------------------------------------------------------------------------
// spmm: side[rows[e]] += vals[e] * x[cols[e]]  (one wave per edge, lane = dim)
// ---------------------------------------------------------------------------
__global__ void spmm_kernel(const int* __restrict__ rows,
                            const int* __restrict__ cols,
                            const float* __restrict__ vals,
                            const float* __restrict__ x,
                            float* __restrict__ side) {
    const int lane = threadIdx.x & 63;
    // force wave-uniformity so edge metadata becomes scalar loads
    const int wave  = __builtin_amdgcn_readfirstlane(
        (blockIdx.x * blockDim.x + threadIdx.x) >> 6);
    const int nwave = (gridDim.x * blockDim.x) >> 6;

    for (int e = wave; e < N_EDGES; e += nwave) {
        int   r = rows[e];          // uniform -> s_load
        int   c = cols[e];          // uniform -> s_load
        float v = vals[e];          // uniform -> s_load
        float xv = x[c * DIM + lane];              // coalesced 256B gather
        unsafeAtomicAdd(&side[r * DIM + lane], v * xv);  // coalesced 256B atomic
    }
}

// ---------------------------------------------------------------------------
// dense: per node:
//   sum = lrelu(side@Wg + bg); bi = lrelu((ego*side)@Wb + bb); e = sum+bi
//   ego <- e (in place);  out[:, (layer+1)*64 : ] = e / max(||e||, 1e-12)
// one wave per node, lane = output dim, weights in registers
// ---------------------------------------------------------------------------
__global__ __launch_bounds__(256)
void dense_kernel(const float* __restrict__ side,
                  float* __restrict__ ego,
                  const float* __restrict__ gc_w,
                  const float* __restrict__ gc_b,
                  const float* __restrict__ bi_w,
                  const float* __restrict__ bi_b,
                  float* __restrict__ out,
                  int layer) {
    const int lane = threadIdx.x & 63;
    const int wave  = __builtin_amdgcn_readfirstlane(
        (blockIdx.x * blockDim.x + threadIdx.x) >> 6);
    const int nwave = (gridDim.x * blockDim.x) >> 6;

    const float* gw = gc_w + layer * DIM * DIM;
    const float* bw = bi_w + layer * DIM * DIM;

    // my output-column of each weight matrix, held in VGPRs
    float gwr[DIM], bwr[DIM];
#pragma unroll
    for (int k = 0; k < DIM; ++k) {
        gwr[k] = gw[k * DIM + lane];
        bwr[k] = bw[k * DIM + lane];
    }
    const float gb = gc_b[layer * DIM + lane];
    const float bb = bi_b[layer * DIM + lane];

    for (int node = wave; node < N_NODES; node += nwave) {
        const float* srow = side + node * DIM;   // uniform base -> scalar loads
        const float* erow = ego  + node * DIM;
        float accg = gb;
        float accb = bb;
#pragma unroll
        for (int k = 0; k < DIM; ++k) {
            float sv = srow[k];
            float ev = erow[k];
            accg += sv * gwr[k];
            accb += (sv * ev) * bwr[k];
        }
        float se = accg > 0.0f ? accg : 0.01f * accg;
        float be = accb > 0.0f ? accb : 0.01f * accb;
        float e  = se + be;

        // wave-wide L2 norm over the 64 dims
        float e2 = e * e;
#pragma unroll
        for (int off = 32; off > 0; off >>= 1)
            e2 += __shfl_xor(e2, off, 64);
        float nv = e / fmaxf(sqrtf(e2), 1e-12f);

        ego[node * DIM + lane] = e;                              // next-layer input
        out[node * OUT_STRIDE + (layer + 1) * DIM + lane] = nv;  // normalized out
    }
}

// ---------------------------------------------------------------------------
extern "C" void kernel_launch(void* const* d_in, const int* in_sizes, int n_in,
                              void* d_out, int out_size, void* d_ws, size_t ws_size,
                              hipStream_t stream) {
    const int*   adj_rows = (const int*)  d_in[0];
    const int*   adj_cols = (const int*)  d_in[1];
    const float* adj_vals = (const float*)d_in[2];
    const float* user_emb = (const float*)d_in[3];
    const float* item_emb = (const float*)d_in[4];
    const float* gc_w     = (const float*)d_in[5];
    const float* gc_b     = (const float*)d_in[6];
    const float* bi_w     = (const float*)d_in[7];
    const float* bi_b     = (const float*)d_in[8];
    float* out = (float*)d_out;

    const size_t feat_bytes = (size_t)N_NODES * DIM * sizeof(float);
    float* side = (float*)d_ws;                                   // 38.4 MB
    float* ego  = (float*)((char*)d_ws + feat_bytes);             // 38.4 MB

    concat_kernel<<<dim3(2048), dim3(256), 0, stream>>>(user_emb, item_emb, ego, out);

    for (int layer = 0; layer < N_LAYERS; ++layer) {
        hipMemsetAsync(side, 0, feat_bytes, stream);
        spmm_kernel<<<dim3(4096), dim3(256), 0, stream>>>(
            adj_rows, adj_cols, adj_vals, ego, side);
        dense_kernel<<<dim3(1024), dim3(256), 0, stream>>>(
            side, ego, gc_w, gc_b, bi_w, bi_b, out, layer);
    }
}

// Round 2
// 3428.643 us; speedup vs baseline: 1.0580x; 1.0580x over previous
//
#include <hip/hip_runtime.h>
#include <hip/hip_bf16.h>

#define N_USERS 100000
#define N_ITEMS 50000
#define N_NODES 150000
#define N_EDGES 4800000
#define DIM 64
#define N_LAYERS 3
#define OUT_STRIDE 256   // DIM * (N_LAYERS+1)
#define EPS 1e-12f
#define SCAN_NB 586      // ceil(150000/256)

// ---------------------------------------------------------------------------
// concat: write ego0 = [user_emb; item_emb] into out slice 0 (cols 0:64), f4
// ---------------------------------------------------------------------------
__global__ void concat_kernel(const float4* __restrict__ user_emb,
                              const float4* __restrict__ item_emb,
                              float4* __restrict__ out) {
    const int total = N_NODES * (DIM / 4);           // 2.4M float4
    for (int i = blockIdx.x * blockDim.x + threadIdx.x; i < total;
         i += gridDim.x * blockDim.x) {
        int node = i >> 4;            // 16 float4 per node row
        int q    = i & 15;
        float4 v = (node < N_USERS) ? user_emb[i] : item_emb[i - N_USERS * 16];
        out[node * (OUT_STRIDE / 4) + q] = v;
    }
}

// ---------------------------------------------------------------------------
// CSR build: histogram -> scan (3 kernels) -> scatter
// ---------------------------------------------------------------------------
__global__ void hist_kernel(const int* __restrict__ rows, int* __restrict__ counts) {
    for (int e = blockIdx.x * blockDim.x + threadIdx.x; e < N_EDGES;
         e += gridDim.x * blockDim.x)
        atomicAdd(&counts[rows[e]], 1);
}

__global__ void scan_a_kernel(const int* __restrict__ counts, int* __restrict__ bsums) {
    int i = blockIdx.x * 256 + threadIdx.x;
    int v = (i < N_NODES) ? counts[i] : 0;
#pragma unroll
    for (int off = 32; off > 0; off >>= 1) v += __shfl_xor(v, off, 64);
    __shared__ int ws4[4];
    if ((threadIdx.x & 63) == 0) ws4[threadIdx.x >> 6] = v;
    __syncthreads();
    if (threadIdx.x == 0) bsums[blockIdx.x] = ws4[0] + ws4[1] + ws4[2] + ws4[3];
}

__global__ void scan_b_kernel(const int* __restrict__ bsums, int* __restrict__ bscan) {
    __shared__ int sd[1024];
    int tid = threadIdx.x;
    int v = (tid < SCAN_NB) ? bsums[tid] : 0;
    sd[tid] = v;
    __syncthreads();
    for (int off = 1; off < 1024; off <<= 1) {
        int t = (tid >= off) ? sd[tid - off] : 0;
        __syncthreads();
        sd[tid] += t;
        __syncthreads();
    }
    if (tid < SCAN_NB) bscan[tid] = sd[tid] - v;   // exclusive
}

__global__ void scan_c_kernel(const int* __restrict__ counts,
                              const int* __restrict__ bscan,
                              int* __restrict__ row_ptr,
                              int* __restrict__ cursor) {
    __shared__ int sd[256];
    int i = blockIdx.x * 256 + threadIdx.x;
    int v = (i < N_NODES) ? counts[i] : 0;
    sd[threadIdx.x] = v;
    __syncthreads();
    for (int off = 1; off < 256; off <<= 1) {
        int t = (threadIdx.x >= off) ? sd[threadIdx.x - off] : 0;
        __syncthreads();
        sd[threadIdx.x] += t;
        __syncthreads();
    }
    if (i < N_NODES) {
        int excl = bscan[blockIdx.x] + sd[threadIdx.x] - v;
        row_ptr[i] = excl;
        cursor[i]  = excl;
    }
    if (i == 0) row_ptr[N_NODES] = N_EDGES;
}

__global__ void scatter_kernel(const int* __restrict__ rows,
                               const int* __restrict__ cols,
                               const float* __restrict__ vals,
                               int* __restrict__ cursor,
                               float2* __restrict__ cv) {
    for (int e = blockIdx.x * blockDim.x + threadIdx.x; e < N_EDGES;
         e += gridDim.x * blockDim.x) {
        int r = rows[e];
        int pos = atomicAdd(&cursor[r], 1);
        cv[pos] = make_float2(__int_as_float(cols[e]), vals[e]);
    }
}

// ---------------------------------------------------------------------------
// fused layer: one wave per destination node (lane = dim)
//   side[lane] = sum over row edges of val * x[col][lane]   (pull, no atomics)
//   accg = side @ gc_w + gc_b ; accb = (ego*side) @ bi_w + bi_b  (readlane bcast)
//   ego_next = lrelu(accg) + lrelu(accb)  -> out slice (layer+1), UNNORMALIZED
// x = out slice `layer` (contiguous 256B per node row)
// ---------------------------------------------------------------------------
__global__ __launch_bounds__(256)
void fused_layer_kernel(const int* __restrict__ row_ptr,
                        const float2* __restrict__ cv,
                        const float* __restrict__ xin,    // out + layer*64
                        float* __restrict__ xout,         // out + (layer+1)*64
                        const float* __restrict__ gc_w,
                        const float* __restrict__ gc_b,
                        const float* __restrict__ bi_w,
                        const float* __restrict__ bi_b,
                        int layer) {
    const int lane  = threadIdx.x & 63;
    const int wave  = (blockIdx.x * blockDim.x + threadIdx.x) >> 6;
    const int nwave = (gridDim.x * blockDim.x) >> 6;

    // my output-column of each weight matrix, held in VGPRs (loaded once/wave)
    float gwr[DIM], bwr[DIM];
#pragma unroll
    for (int k = 0; k < DIM; ++k) {
        gwr[k] = gc_w[layer * DIM * DIM + k * DIM + lane];
        bwr[k] = bi_w[layer * DIM * DIM + k * DIM + lane];
    }
    const float gb = gc_b[layer * DIM + lane];
    const float bb = bi_b[layer * DIM + lane];

    for (int node = wave; node < N_NODES; node += nwave) {
        const int start = row_ptr[node];
        const int end   = row_ptr[node + 1];

        float acc = 0.0f;                      // side[node][lane]
        int j = start;
        while (j < end) {
            int m = end - j;
            if (m > 64) m = 64;
            float2 p = make_float2(0.0f, 0.0f);
            if (lane < m) p = cv[j + lane];    // batch edge metadata, coalesced
            for (int t = 0; t < m; t += 8) {   // 8-deep pipelined gathers
                int cnt = m - t; if (cnt > 8) cnt = 8;
                float g[8], vv[8];
#pragma unroll
                for (int u = 0; u < 8; ++u) {
                    if (u < cnt) {
                        int col = __float_as_int(__shfl(p.x, t + u, 64));
                        vv[u] = __shfl(p.y, t + u, 64);
                        g[u]  = xin[col * OUT_STRIDE + lane];
                    }
                }
#pragma unroll
                for (int u = 0; u < 8; ++u)
                    if (u < cnt) acc = fmaf(vv[u], g[u], acc);
            }
            j += m;
        }

        // dense branches: broadcast side[k], ego[k] via readlane
        float ev = xin[node * OUT_STRIDE + lane];   // ego[node][lane]
        float accg = gb, accb = bb;
#pragma unroll
        for (int k = 0; k < DIM; ++k) {
            float sk = __shfl(acc, k, 64);
            float ek = __shfl(ev,  k, 64);
            accg = fmaf(sk, gwr[k], accg);
            accb = fmaf(sk * ek, bwr[k], accb);
        }
        float se = accg > 0.0f ? accg : 0.01f * accg;
        float be = accb > 0.0f ? accb : 0.01f * accb;
        xout[node * OUT_STRIDE + lane] = se + be;   // unnormalized ego_{l+1}
    }
}

// ---------------------------------------------------------------------------
// final pass: L2-normalize out slices 1..3 in place (wave per node)
// ---------------------------------------------------------------------------
__global__ void norm_kernel(float* __restrict__ out) {
    const int lane  = threadIdx.x & 63;
    const int wave  = (blockIdx.x * blockDim.x + threadIdx.x) >> 6;
    const int nwave = (gridDim.x * blockDim.x) >> 6;
    for (int node = wave; node < N_NODES; node += nwave) {
#pragma unroll
        for (int s = 1; s <= N_LAYERS; ++s) {
            float v = out[node * OUT_STRIDE + s * DIM + lane];
            float e2 = v * v;
#pragma unroll
            for (int off = 32; off > 0; off >>= 1)
                e2 += __shfl_xor(e2, off, 64);
            out[node * OUT_STRIDE + s * DIM + lane] = v / fmaxf(sqrtf(e2), EPS);
        }
    }
}

// ---------------------------------------------------------------------------
extern "C" void kernel_launch(void* const* d_in, const int* in_sizes, int n_in,
                              void* d_out, int out_size, void* d_ws, size_t ws_size,
                              hipStream_t stream) {
    const int*   adj_rows = (const int*)  d_in[0];
    const int*   adj_cols = (const int*)  d_in[1];
    const float* adj_vals = (const float*)d_in[2];
    const float* user_emb = (const float*)d_in[3];
    const float* item_emb = (const float*)d_in[4];
    const float* gc_w     = (const float*)d_in[5];
    const float* gc_b     = (const float*)d_in[6];
    const float* bi_w     = (const float*)d_in[7];
    const float* bi_b     = (const float*)d_in[8];
    float* out = (float*)d_out;

    // ws layout
    char* p = (char*)d_ws;
    float2* cv      = (float2*)p;                 p += (size_t)N_EDGES * 8;     // 38.4 MB
    int*    row_ptr = (int*)p;                    p += (size_t)(N_NODES + 1) * 4;
    int*    cursor  = (int*)p;                    p += (size_t)N_NODES * 4;
    int*    counts  = (int*)p;                    p += (size_t)N_NODES * 4;
    int*    bsums   = (int*)p;                    p += (size_t)SCAN_NB * 4;
    int*    bscan   = (int*)p;

    // slice 0 = raw ego0
    concat_kernel<<<dim3(2048), dim3(256), 0, stream>>>(
        (const float4*)user_emb, (const float4*)item_emb, (float4*)out);

    // CSR build
    hipMemsetAsync(counts, 0, (size_t)N_NODES * 4, stream);
    hist_kernel<<<dim3(2048), dim3(256), 0, stream>>>(adj_rows, counts);
    scan_a_kernel<<<dim3(SCAN_NB), dim3(256), 0, stream>>>(counts, bsums);
    scan_b_kernel<<<dim3(1), dim3(1024), 0, stream>>>(bsums, bscan);
    scan_c_kernel<<<dim3(SCAN_NB), dim3(256), 0, stream>>>(counts, bscan, row_ptr, cursor);
    scatter_kernel<<<dim3(2048), dim3(256), 0, stream>>>(
        adj_rows, adj_cols, adj_vals, cursor, cv);

    // layers: gather from slice l, write unnormalized ego into slice l+1
    for (int layer = 0; layer < N_LAYERS; ++layer) {
        fused_layer_kernel<<<dim3(1024), dim3(256), 0, stream>>>(
            row_ptr, cv, out + layer * DIM, out + (layer + 1) * DIM,
            gc_w, gc_b, bi_w, bi_b, layer);
    }

    // normalize slices 1..3 in place
    norm_kernel<<<dim3(2048), dim3(256), 0, stream>>>(out);
}

// Round 4
// 1686.265 us; speedup vs baseline: 2.1511x; 2.0333x over previous
//
#include <hip/hip_runtime.h>
#include <hip/hip_bf16.h>

#define N_USERS 100000
#define N_ITEMS 50000
#define N_NODES 150000
#define N_EDGES 4800000
#define DIM 64
#define N_LAYERS 3
#define OUT_STRIDE 256   // DIM * (N_LAYERS+1)
#define EPS 1e-12f
#define SCAN_NB 586      // ceil(150000/256)

// ---------------------------------------------------------------------------
// concat: write ego0 = [user_emb; item_emb] into out slice 0 (cols 0:64), f4
// ---------------------------------------------------------------------------
__global__ void concat_kernel(const float4* __restrict__ user_emb,
                              const float4* __restrict__ item_emb,
                              float4* __restrict__ out) {
    const int total = N_NODES * (DIM / 4);           // 2.4M float4
    for (int i = blockIdx.x * blockDim.x + threadIdx.x; i < total;
         i += gridDim.x * blockDim.x) {
        int node = i >> 4;            // 16 float4 per node row
        int q    = i & 15;
        float4 v = (node < N_USERS) ? user_emb[i] : item_emb[i - N_USERS * 16];
        out[node * (OUT_STRIDE / 4) + q] = v;
    }
}

// ---------------------------------------------------------------------------
// CSR build: histogram -> scan (3 kernels) -> scatter
// ---------------------------------------------------------------------------
__global__ void hist_kernel(const int* __restrict__ rows, int* __restrict__ counts) {
    for (int e = blockIdx.x * blockDim.x + threadIdx.x; e < N_EDGES;
         e += gridDim.x * blockDim.x)
        atomicAdd(&counts[rows[e]], 1);
}

__global__ void scan_a_kernel(const int* __restrict__ counts, int* __restrict__ bsums) {
    int i = blockIdx.x * 256 + threadIdx.x;
    int v = (i < N_NODES) ? counts[i] : 0;
#pragma unroll
    for (int off = 32; off > 0; off >>= 1) v += __shfl_xor(v, off, 64);
    __shared__ int ws4[4];
    if ((threadIdx.x & 63) == 0) ws4[threadIdx.x >> 6] = v;
    __syncthreads();
    if (threadIdx.x == 0) bsums[blockIdx.x] = ws4[0] + ws4[1] + ws4[2] + ws4[3];
}

__global__ void scan_b_kernel(const int* __restrict__ bsums, int* __restrict__ bscan) {
    __shared__ int sd[1024];
    int tid = threadIdx.x;
    int v = (tid < SCAN_NB) ? bsums[tid] : 0;
    sd[tid] = v;
    __syncthreads();
    for (int off = 1; off < 1024; off <<= 1) {
        int t = (tid >= off) ? sd[tid - off] : 0;
        __syncthreads();
        sd[tid] += t;
        __syncthreads();
    }
    if (tid < SCAN_NB) bscan[tid] = sd[tid] - v;   // exclusive
}

__global__ void scan_c_kernel(const int* __restrict__ counts,
                              const int* __restrict__ bscan,
                              int* __restrict__ row_ptr,
                              int* __restrict__ cursor) {
    __shared__ int sd[256];
    int i = blockIdx.x * 256 + threadIdx.x;
    int v = (i < N_NODES) ? counts[i] : 0;
    sd[threadIdx.x] = v;
    __syncthreads();
    for (int off = 1; off < 256; off <<= 1) {
        int t = (threadIdx.x >= off) ? sd[threadIdx.x - off] : 0;
        __syncthreads();
        sd[threadIdx.x] += t;
        __syncthreads();
    }
    if (i < N_NODES) {
        int excl = bscan[blockIdx.x] + sd[threadIdx.x] - v;
        row_ptr[i] = excl;
        cursor[i]  = excl;
    }
    if (i == 0) row_ptr[N_NODES] = N_EDGES;
}

__global__ void scatter_kernel(const int* __restrict__ rows,
                               const int* __restrict__ cols,
                               const float* __restrict__ vals,
                               int* __restrict__ cursor,
                               float2* __restrict__ cv) {
    for (int e = blockIdx.x * blockDim.x + threadIdx.x; e < N_EDGES;
         e += gridDim.x * blockDim.x) {
        int r = rows[e];
        int pos = atomicAdd(&cursor[r], 1);
        cv[pos] = make_float2(__int_as_float(cols[e]), vals[e]);
    }
}

// ---------------------------------------------------------------------------
// spmm pull: one wave per node, lane = dim. Edge metadata via SCALAR loads
// (wave-uniform index -> s_load_dwordx16), gathers 16-deep in flight.
// Writes side row (unweighted) into out slice l+1.
// ---------------------------------------------------------------------------
__global__ __launch_bounds__(256, 8)
void spmm_pull_kernel(const int* __restrict__ row_ptr,
                      const float2* __restrict__ cv,
                      const float* __restrict__ xin,    // out + layer*64
                      float* __restrict__ xside) {      // out + (layer+1)*64
    const int lane  = threadIdx.x & 63;
    const int wave  = __builtin_amdgcn_readfirstlane(
        (blockIdx.x * blockDim.x + threadIdx.x) >> 6);
    const int nwave = (gridDim.x * blockDim.x) >> 6;

    for (int node = wave; node < N_NODES; node += nwave) {
        const int start = __builtin_amdgcn_readfirstlane(row_ptr[node]);
        const int end   = __builtin_amdgcn_readfirstlane(row_ptr[node + 1]);

        float acc = 0.0f;
        int j = start;
        // full groups of 16: contiguous scalar metadata, 16 gathers in flight
        for (; j + 16 <= end; j += 16) {
            float g[16], vv[16];
#pragma unroll
            for (int u = 0; u < 16; ++u) {
                float2 p = cv[j + u];                       // uniform -> s_load
                int c = __builtin_amdgcn_readfirstlane(__float_as_int(p.x));
                vv[u] = p.y;
                g[u]  = xin[c * OUT_STRIDE + lane];         // 256B coalesced
            }
#pragma unroll
            for (int u = 0; u < 16; ++u) acc = fmaf(vv[u], g[u], acc);
        }
        // tail (< 16 edges): clamp index, zero the value for OOB slots
        if (j < end) {
            const int cnt = end - j;
            float g[16], vv[16];
#pragma unroll
            for (int u = 0; u < 16; ++u) {
                int idx = (u < cnt) ? j + u : end - 1;
                float2 p = cv[idx];
                int c = __builtin_amdgcn_readfirstlane(__float_as_int(p.x));
                vv[u] = (u < cnt) ? p.y : 0.0f;
                g[u]  = xin[c * OUT_STRIDE + lane];
            }
#pragma unroll
            for (int u = 0; u < 16; ++u) acc = fmaf(vv[u], g[u], acc);
        }
        xside[node * OUT_STRIDE + lane] = acc;
    }
}

// ---------------------------------------------------------------------------
// dense: rewrite slice l+1 in place:  new = lrelu(side@Wg+bg)+lrelu((ego*side)@Wb+bb)
// weights in VGPRs; side/ego rows broadcast via per-wave LDS float4 reads
// ---------------------------------------------------------------------------
__global__ __launch_bounds__(256)
void dense_kernel(const float* __restrict__ xego,   // out + layer*64 (read)
                  float* __restrict__ xside,        // out + (layer+1)*64 (rw)
                  const float* __restrict__ gc_w,
                  const float* __restrict__ gc_b,
                  const float* __restrict__ bi_w,
                  const float* __restrict__ bi_b,
                  int layer) {
    __shared__ float sh[4][2][DIM];
    const int lane  = threadIdx.x & 63;
    const int wslot = threadIdx.x >> 6;
    const int wave  = (blockIdx.x * blockDim.x + threadIdx.x) >> 6;
    const int nwave = (gridDim.x * blockDim.x) >> 6;

    float gwr[DIM], bwr[DIM];
#pragma unroll
    for (int k = 0; k < DIM; ++k) {
        gwr[k] = gc_w[layer * DIM * DIM + k * DIM + lane];
        bwr[k] = bi_w[layer * DIM * DIM + k * DIM + lane];
    }
    const float gb = gc_b[layer * DIM + lane];
    const float bb = bi_b[layer * DIM + lane];

    for (int node = wave; node < N_NODES; node += nwave) {
        float sv = xside[node * OUT_STRIDE + lane];
        float ev = xego [node * OUT_STRIDE + lane];
        sh[wslot][0][lane] = sv;
        sh[wslot][1][lane] = ev;
        float accg = gb, accb = bb;
        const float4* s4 = (const float4*)sh[wslot][0];
        const float4* e4 = (const float4*)sh[wslot][1];
#pragma unroll
        for (int k4 = 0; k4 < DIM / 4; ++k4) {
            float4 s = s4[k4];        // uniform addr -> conflict-free broadcast
            float4 e = e4[k4];
            accg = fmaf(s.x, gwr[4*k4+0], accg); accb = fmaf(s.x*e.x, bwr[4*k4+0], accb);
            accg = fmaf(s.y, gwr[4*k4+1], accg); accb = fmaf(s.y*e.y, bwr[4*k4+1], accb);
            accg = fmaf(s.z, gwr[4*k4+2], accg); accb = fmaf(s.z*e.z, bwr[4*k4+2], accb);
            accg = fmaf(s.w, gwr[4*k4+3], accg); accb = fmaf(s.w*e.w, bwr[4*k4+3], accb);
        }
        float se = accg > 0.0f ? accg : 0.01f * accg;
        float be = accb > 0.0f ? accb : 0.01f * accb;
        xside[node * OUT_STRIDE + lane] = se + be;   // unnormalized ego_{l+1}
    }
}

// ---------------------------------------------------------------------------
// final pass: L2-normalize out slices 1..3 in place (wave per node)
// ---------------------------------------------------------------------------
__global__ void norm_kernel(float* __restrict__ out) {
    const int lane  = threadIdx.x & 63;
    const int wave  = (blockIdx.x * blockDim.x + threadIdx.x) >> 6;
    const int nwave = (gridDim.x * blockDim.x) >> 6;
    for (int node = wave; node < N_NODES; node += nwave) {
#pragma unroll
        for (int s = 1; s <= N_LAYERS; ++s) {
            float v = out[node * OUT_STRIDE + s * DIM + lane];
            float e2 = v * v;
#pragma unroll
            for (int off = 32; off > 0; off >>= 1)
                e2 += __shfl_xor(e2, off, 64);
            out[node * OUT_STRIDE + s * DIM + lane] = v / fmaxf(sqrtf(e2), EPS);
        }
    }
}

// ---------------------------------------------------------------------------
extern "C" void kernel_launch(void* const* d_in, const int* in_sizes, int n_in,
                              void* d_out, int out_size, void* d_ws, size_t ws_size,
                              hipStream_t stream) {
    const int*   adj_rows = (const int*)  d_in[0];
    const int*   adj_cols = (const int*)  d_in[1];
    const float* adj_vals = (const float*)d_in[2];
    const float* user_emb = (const float*)d_in[3];
    const float* item_emb = (const float*)d_in[4];
    const float* gc_w     = (const float*)d_in[5];
    const float* gc_b     = (const float*)d_in[6];
    const float* bi_w     = (const float*)d_in[7];
    const float* bi_b     = (const float*)d_in[8];
    float* out = (float*)d_out;

    // ws layout (~40.4 MB)
    char* p = (char*)d_ws;
    float2* cv      = (float2*)p;                 p += (size_t)N_EDGES * 8;     // 38.4 MB
    int*    row_ptr = (int*)p;                    p += (size_t)(N_NODES + 1) * 4;
    int*    cursor  = (int*)p;                    p += (size_t)N_NODES * 4;
    int*    counts  = (int*)p;                    p += (size_t)N_NODES * 4;
    int*    bsums   = (int*)p;                    p += (size_t)SCAN_NB * 4;
    int*    bscan   = (int*)p;

    // slice 0 = raw ego0
    concat_kernel<<<dim3(2048), dim3(256), 0, stream>>>(
        (const float4*)user_emb, (const float4*)item_emb, (float4*)out);

    // CSR build
    hipMemsetAsync(counts, 0, (size_t)N_NODES * 4, stream);
    hist_kernel<<<dim3(2048), dim3(256), 0, stream>>>(adj_rows, counts);
    scan_a_kernel<<<dim3(SCAN_NB), dim3(256), 0, stream>>>(counts, bsums);
    scan_b_kernel<<<dim3(1), dim3(1024), 0, stream>>>(bsums, bscan);
    scan_c_kernel<<<dim3(SCAN_NB), dim3(256), 0, stream>>>(counts, bscan, row_ptr, cursor);
    scatter_kernel<<<dim3(2048), dim3(256), 0, stream>>>(
        adj_rows, adj_cols, adj_vals, cursor, cv);

    // layers: spmm (gather-only, max occupancy) then dense (in-place rewrite)
    for (int layer = 0; layer < N_LAYERS; ++layer) {
        spmm_pull_kernel<<<dim3(2048), dim3(256), 0, stream>>>(
            row_ptr, cv, out + layer * DIM, out + (layer + 1) * DIM);
        dense_kernel<<<dim3(768), dim3(256), 0, stream>>>(
            out + layer * DIM, out + (layer + 1) * DIM,
            gc_w, gc_b, bi_w, bi_b, layer);
    }

    // normalize slices 1..3 in place
    norm_kernel<<<dim3(2048), dim3(256), 0, stream>>>(out);
}